// Round 11
// baseline (1599.385 us; speedup 1.0000x reference)
//
#include <hip/hip_runtime.h>

#define Bsz  512
#define FEAT 2048
#define Hd   512
#define Vd   100
#define Td   200
#define Gd   2048   // gatecols; per 8-hcol group (32 gc): [r×8|z×8|in×8|hn×8]

typedef __bf16 bf16;
typedef __bf16 bf16x8 __attribute__((ext_vector_type(8)));
typedef float  f32x4  __attribute__((ext_vector_type(4)));

// Static device storage. Rewritten every launch -> deterministic across replays.
__device__ bf16  g_hbuf[Td + 1][Bsz][Hd];   // h history (k_proj input); bulk-flushed
__device__ bf16  g_hstage[8][Bsz][Hd];      // L2-resident 8-slot exchange ring
__device__ bf16  g_wt0[Gd][Hd];             // step-0 weights   [gatecol][k]
__device__ bf16  g_wt1[Gd][Hd];             // steps>=1 weights [gatecol][k]
__device__ float g_bias0[Gd];
__device__ float g_bias1[Gd];
__device__ bf16  g_featbf[Bsz][FEAT];
__device__ bf16  g_whpt[Hd][FEAT];          // w_hp transposed: [n][k]
__device__ bf16  g_wprojt[112][Hd];         // w_proj transposed+padded: [v][k]
__device__ float g_gi0[3 * Hd];             // embed[SOS] @ w_ih.T + b_ih
__device__ unsigned g_dbar[32][16];         // [rowgroup][0]: arrival counter (64B apart)
__device__ unsigned g_xcd[256];             // published XCC_ID per block
__device__ unsigned g_pub;                  // publish barrier counter

// ---------- device-coherent (L3, sc0 sc1) helpers — slow path ----------
template <int OFF>
__device__ __forceinline__ bf16x8 ld_b16x8_cohere(const void* p) {
  bf16x8 r;
  asm volatile("global_load_dwordx4 %0, %1, off offset:%2 sc0 sc1"
               : "=&v"(r) : "v"(p), "i"(OFF) : "memory");
  return r;
}
// ---------- agent-scope (L1-bypass, L2-hit, sc1) loads — fast path ----------
template <int OFF>
__device__ __forceinline__ bf16x8 ld_b16x8_l2(const void* p) {
  bf16x8 r;
  asm volatile("global_load_dwordx4 %0, %1, off offset:%2 sc1"
               : "=&v"(r) : "v"(p), "i"(OFF) : "memory");
  return r;
}
template <int OFF>
__device__ __forceinline__ void st_u16_cohere(void* p, unsigned short v) {
  asm volatile("global_store_short %0, %1, off offset:%2 sc0 sc1"
               :: "v"(p), "v"(v), "i"(OFF) : "memory");
}
__device__ __forceinline__ void st_u32_cohere(void* p, unsigned v) {
  asm volatile("global_store_dword %0, %1, off sc0 sc1" :: "v"(p), "v"(v) : "memory");
}
__device__ __forceinline__ unsigned ld_u32_cohere(const void* p) {
  unsigned r;
  asm volatile("global_load_dword %0, %1, off sc0 sc1\n\ts_waitcnt vmcnt(0)"
               : "=&v"(r) : "v"(p) : "memory");
  return r;
}
// ---------- atomic helpers (device-scope; L1-proof reads — round-4 lesson) ----------
__device__ __forceinline__ unsigned atomic_rd(unsigned* p) {
  unsigned r;
  asm volatile("global_atomic_add %0, %1, %2, off sc0\n\ts_waitcnt vmcnt(0)"
               : "=&v"(r) : "v"(p), "v"(0u) : "memory");
  return r;
}
__device__ __forceinline__ void atomic_inc(unsigned* p) {
  asm volatile("global_atomic_add %0, %1, off" :: "v"(p), "v"(1u) : "memory");
}
__device__ __forceinline__ void wait_vm0() { asm volatile("s_waitcnt vmcnt(0)" ::: "memory"); }
__device__ __forceinline__ void wait_vm8() { asm volatile("s_waitcnt vmcnt(8)" ::: "memory"); }

#define LDA16(arr, base) do {                                                   \
  arr[0]  = ld_b16x8_cohere<0>(base);   arr[1]  = ld_b16x8_cohere<64>(base);    \
  arr[2]  = ld_b16x8_cohere<128>(base); arr[3]  = ld_b16x8_cohere<192>(base);   \
  arr[4]  = ld_b16x8_cohere<256>(base); arr[5]  = ld_b16x8_cohere<320>(base);   \
  arr[6]  = ld_b16x8_cohere<384>(base); arr[7]  = ld_b16x8_cohere<448>(base);   \
  arr[8]  = ld_b16x8_cohere<512>(base); arr[9]  = ld_b16x8_cohere<576>(base);   \
  arr[10] = ld_b16x8_cohere<640>(base); arr[11] = ld_b16x8_cohere<704>(base);   \
  arr[12] = ld_b16x8_cohere<768>(base); arr[13] = ld_b16x8_cohere<832>(base);   \
  arr[14] = ld_b16x8_cohere<896>(base); arr[15] = ld_b16x8_cohere<960>(base);   \
} while (0)

#define LDA16_L2(arr, base) do {                                                \
  arr[0]  = ld_b16x8_l2<0>(base);   arr[1]  = ld_b16x8_l2<64>(base);            \
  arr[2]  = ld_b16x8_l2<128>(base); arr[3]  = ld_b16x8_l2<192>(base);           \
  arr[4]  = ld_b16x8_l2<256>(base); arr[5]  = ld_b16x8_l2<320>(base);           \
  arr[6]  = ld_b16x8_l2<384>(base); arr[7]  = ld_b16x8_l2<448>(base);           \
  arr[8]  = ld_b16x8_l2<512>(base); arr[9]  = ld_b16x8_l2<576>(base);           \
  arr[10] = ld_b16x8_l2<640>(base); arr[11] = ld_b16x8_l2<704>(base);           \
  arr[12] = ld_b16x8_l2<768>(base); arr[13] = ld_b16x8_l2<832>(base);           \
  arr[14] = ld_b16x8_l2<896>(base); arr[15] = ld_b16x8_l2<960>(base);           \
} while (0)

__device__ __forceinline__ float sigmoidf_(float x) {
  x = fminf(fmaxf(x, -30.f), 30.f);
  return 1.f / (1.f + __expf(-x));
}
__device__ __forceinline__ float tanhf_(float x) {
  x = fminf(fmaxf(x, -15.f), 15.f);
  float e = __expf(2.f * x);
  return (e - 1.f) / (e + 1.f);
}

// ---------- prep kernels ----------

__global__ void k_conv_feat(const float* feat) {
  int i = blockIdx.x * 256 + threadIdx.x;
  if (i < Bsz * FEAT) ((bf16*)g_featbf)[i] = (bf16)feat[i];
  if (blockIdx.x == 0) {  // reset sync state each replay
    ((unsigned*)g_dbar)[threadIdx.x] = 0u;
    ((unsigned*)g_dbar)[256 + threadIdx.x] = 0u;
    g_xcd[threadIdx.x] = 0xffffffffu;
    if (threadIdx.x == 0) g_pub = 0u;
  }
}

__global__ void k_gi0(const float* embed, const float* w_ih, const float* b_ih) {
  int j = blockIdx.x;
  const float* wr = w_ih + (size_t)j * Hd;
  float s = 0.f;
  for (int k = threadIdx.x; k < Hd; k += 64) s += embed[k] * wr[k];
#pragma unroll
  for (int off = 32; off > 0; off >>= 1) s += __shfl_down(s, off);
  if (threadIdx.x == 0) g_gi0[j] = s + b_ih[j];
}

// gate col c: group g=c>>5 (8 hcols), slot=(c>>3)&3 in {r,z,in,hn}, j=g*8+(c&7)
__global__ void k_build_wt1(const float* w_ih, const float* w_hh,
                            const float* b_ih, const float* b_hh) {
  int c = blockIdx.x;
  int j = (c >> 5) * 8 + (c & 7);
  int f = (c >> 3) & 3;
  const float* s1 = nullptr; const float* s2 = nullptr; float bias;
  if (f == 0)      { s1 = w_ih + (size_t)j * Hd;            s2 = w_hh + (size_t)j * Hd;            bias = b_ih[j] + b_hh[j]; }
  else if (f == 1) { s1 = w_ih + (size_t)(Hd + j) * Hd;     s2 = w_hh + (size_t)(Hd + j) * Hd;     bias = b_ih[Hd + j] + b_hh[Hd + j]; }
  else if (f == 2) { s1 = w_ih + (size_t)(2 * Hd + j) * Hd;                                        bias = b_ih[2 * Hd + j]; }
  else             { s1 = w_hh + (size_t)(2 * Hd + j) * Hd;                                        bias = b_hh[2 * Hd + j]; }
  for (int k = threadIdx.x; k < Hd; k += 256) {
    float v = s1[k] + (s2 ? s2[k] : 0.f);
    g_wt1[c][k] = (bf16)v;
  }
  if (threadIdx.x == 0) g_bias1[c] = bias;
}

__global__ void k_build_wt0(const float* w_hh, const float* b_hh) {
  int c = blockIdx.x;
  int j = (c >> 5) * 8 + (c & 7);
  int f = (c >> 3) & 3;
  const float* s1 = nullptr; float bias;
  if (f == 0)      { s1 = w_hh + (size_t)j * Hd;            bias = g_gi0[j] + b_hh[j]; }
  else if (f == 1) { s1 = w_hh + (size_t)(Hd + j) * Hd;     bias = g_gi0[Hd + j] + b_hh[Hd + j]; }
  else if (f == 2) {                                        bias = g_gi0[2 * Hd + j]; }
  else             { s1 = w_hh + (size_t)(2 * Hd + j) * Hd; bias = b_hh[2 * Hd + j]; }
  for (int k = threadIdx.x; k < Hd; k += 256)
    g_wt0[c][k] = (bf16)(s1 ? s1[k] : 0.f);
  if (threadIdx.x == 0) g_bias0[c] = bias;
}

__global__ void k_build_whpt(const float* w_hp) {
  int n = blockIdx.x;
  for (int k = threadIdx.x; k < FEAT; k += 256)
    g_whpt[n][k] = (bf16)w_hp[(size_t)k * Hd + n];
}

__global__ void k_build_wprojt(const float* w_proj) {
  int v = blockIdx.x;  // 0..111
  for (int k = threadIdx.x; k < Hd; k += 256)
    g_wprojt[v][k] = (bf16)(v < Vd ? w_proj[(size_t)k * Vd + v] : 0.f);
}

// ---------- persistent kernel: h0 + 200 GRU steps, TWO chains per wave ----------
// Wave (x=bid&7, i=bid>>3, w): oct=(i>>2)*4+w+32*(i&1 of j) -> 8 hcols, 32 gc,
// weights Bw[32]=128 VGPR SHARED by both chains. chainA rows rgA=x*4+(i&3),
// chainB rows rgB=x*4+((i&3)^1). Coverage of each rowgroup's 64 octs is exactly
// complementary (A: half, B: other half). Phase A and phase B alternate each
// step; each barrier's post->wait gap contains the opposite phase's compute,
// hiding the sync round-trips that rounds 6-10 left exposed. No __syncthreads
// in the loop. 64 posts per rowgroup counter per step; leader wave polls, LDS
// flag releases. Stage ring (8 slots) + 8-step history flush as round 10.
__global__ __launch_bounds__(256, 1) void k_gru_seq(const float* b_hp) {
  const int bid = blockIdx.x;
  const int x = bid & 7;            // XCD under round-robin dispatch
  const int i = bid >> 3;           // 0..31
  const int j = i & 3;
  const int w = threadIdx.x >> 6, l = threadIdx.x & 63;
  const int m = l & 15;
  const int ksub = (l >> 4) * 8;
  const int rgA = x * 4 + j;
  const int rgB = x * 4 + (j ^ 1);
  const int oct = (i >> 2) * 4 + w + 32 * (j & 1);  // 0..63
  const int gcb = oct * 32;
  const int hbase = oct * 8;
  const int arowA = rgA * 16 + m,  arowB = rgB * 16 + m;
  const int srowA = rgA * 16 + (l >> 4) * 4, srowB = rgB * 16 + (l >> 4) * 4;
  const int hc = hbase + (m & 7);
  __shared__ int s_fast;
  __shared__ int s_relA, s_relB;

  // shared persistent B-fragments: 2 col-frags x 16 k-chunks = 128 VGPR
  bf16x8 Bw[32];
#pragma unroll
  for (int f = 0; f < 2; f++)
#pragma unroll
    for (int k0 = 0; k0 < 16; k0++)
      Bw[f * 16 + k0] = *(const bf16x8*)&g_wt1[gcb + f * 16 + m][k0 * 32 + ksub];
  float b0v[2], b1v[2];
#pragma unroll
  for (int f = 0; f < 2; f++) {
    b0v[f] = g_bias0[gcb + f * 16 + m];
    b1v[f] = g_bias1[gcb + f * 16 + m];
  }

  // ---- publish XCC_ID + device publish barrier, decide fast/slow ----
  unsigned xcc;
  asm volatile("s_getreg_b32 %0, hwreg(HW_REG_XCC_ID)" : "=s"(xcc));
  if (threadIdx.x == 0) {
    s_relA = 0; s_relB = 0;
    st_u32_cohere(&g_xcd[bid], xcc);
    wait_vm0();
    atomic_inc(&g_pub);
    while (atomic_rd(&g_pub) < 256u) __builtin_amdgcn_s_sleep(4);
  }
  __syncthreads();
  if (threadIdx.x < 64) {
    unsigned peer = ld_u32_cohere(&g_xcd[x + 8 * (threadIdx.x & 31)]);
    unsigned long long bal = __ballot(peer == xcc);
    if (threadIdx.x == 0) s_fast = (bal == ~0ull) ? 1 : 0;
  }
  __syncthreads();
  const bool fast = (s_fast != 0);

  unsigned* cntA = &g_dbar[rgA][0];
  unsigned* cntB = &g_dbar[rgB][0];

  // ---- h0 for both chains: 16 rows x 8 hcols each (cols duplicated in frag) ----
  float hcA[4], hcB[4];
#pragma unroll
  for (int ch = 0; ch < 2; ch++) {
    const int arow = ch ? arowB : arowA;
    const int srow = ch ? srowB : srowA;
    float* hcar = ch ? hcB : hcA;
    f32x4 acc = {0.f, 0.f, 0.f, 0.f};
#pragma unroll 4
    for (int k0 = 0; k0 < FEAT; k0 += 32) {
      bf16x8 a = *(const bf16x8*)&g_featbf[arow][k0 + ksub];
      bf16x8 b = *(const bf16x8*)&g_whpt[hc][k0 + ksub];
      acc = __builtin_amdgcn_mfma_f32_16x16x32_bf16(a, b, acc, 0, 0, 0);
    }
    float bhp = b_hp[hc];
    unsigned short us[4];
#pragma unroll
    for (int q = 0; q < 4; q++) {
      bf16 hv = (bf16)(acc[q] + bhp);
      hcar[q] = (float)hv;
      us[q] = __builtin_bit_cast(unsigned short, hv);
    }
    if (m < 8) {
      char* pc = (char*)&g_hstage[0][srow][hc];
      if (fast) {
        bf16* pp = (bf16*)pc;
#pragma unroll
        for (int q = 0; q < 4; q++) pp[q * Hd] = __builtin_bit_cast(bf16, us[q]);
      } else {
        st_u16_cohere<0>(pc, us[0]);    st_u16_cohere<1024>(pc, us[1]);
        st_u16_cohere<2048>(pc, us[2]); st_u16_cohere<3072>(pc, us[3]);
      }
    }
  }
  wait_vm0();
  if (l == 0) { atomic_inc(cntA); atomic_inc(cntB); }

  // ---- main loop: phase A then phase B per step ----
  for (int t = 0; t < Td; t++) {
    const int tgt = 64 * (t + 1);

#pragma unroll
    for (int ch = 0; ch < 2; ch++) {
      unsigned* cnt = ch ? cntB : cntA;
      const int arow = ch ? arowB : arowA;
      const int srow = ch ? srowB : srowA;
      float* hcar = ch ? hcB : hcA;

      // barrier: leader wave polls the counter, releases via LDS flag
      if (w == 0) {
        if (l == 0) {
          while ((int)atomic_rd(cnt) < tgt) { }
          __hip_atomic_store(ch ? &s_relB : &s_relA, t + 1,
                             __ATOMIC_RELEASE, __HIP_MEMORY_SCOPE_WORKGROUP);
        }
      } else {
        int* rel = ch ? &s_relB : &s_relA;
        while (__hip_atomic_load(rel, __ATOMIC_ACQUIRE, __HIP_MEMORY_SCOPE_WORKGROUP) < t + 1) { }
      }

      // A-slice of h[t]: 16 rows x 512 k from the stage ring
      bf16x8 a[16];
      const char* Ap = (const char*)&g_hstage[t & 7][arow][ksub];
      if (fast) { LDA16_L2(a, Ap); } else { LDA16(a, Ap); }

      f32x4 acc0a, acc0b, acc1a, acc1b;
      {
        float bf0 = (t == 0) ? b0v[0] : b1v[0];
        float bf1 = (t == 0) ? b0v[1] : b1v[1];
        acc0a = (f32x4){bf0, bf0, bf0, bf0};
        acc1a = (f32x4){bf1, bf1, bf1, bf1};
        acc0b = (f32x4){0.f, 0.f, 0.f, 0.f};
        acc1b = (f32x4){0.f, 0.f, 0.f, 0.f};
      }
      wait_vm8(); __builtin_amdgcn_sched_barrier(0);
      if (t == 0) {  // step-0 weight set streamed from cache once per chain
#pragma unroll
        for (int k0 = 0; k0 < 8; k0++) {
          bf16x8 w0 = *(const bf16x8*)&g_wt0[gcb + m][k0 * 32 + ksub];
          bf16x8 w1 = *(const bf16x8*)&g_wt0[gcb + 16 + m][k0 * 32 + ksub];
          acc0a = __builtin_amdgcn_mfma_f32_16x16x32_bf16(a[k0], w0, acc0a, 0, 0, 0);
          acc1a = __builtin_amdgcn_mfma_f32_16x16x32_bf16(a[k0], w1, acc1a, 0, 0, 0);
        }
        wait_vm0(); __builtin_amdgcn_sched_barrier(0);
#pragma unroll
        for (int k0 = 8; k0 < 16; k0++) {
          bf16x8 w0 = *(const bf16x8*)&g_wt0[gcb + m][k0 * 32 + ksub];
          bf16x8 w1 = *(const bf16x8*)&g_wt0[gcb + 16 + m][k0 * 32 + ksub];
          acc0b = __builtin_amdgcn_mfma_f32_16x16x32_bf16(a[k0], w0, acc0b, 0, 0, 0);
          acc1b = __builtin_amdgcn_mfma_f32_16x16x32_bf16(a[k0], w1, acc1b, 0, 0, 0);
        }
      } else {
#pragma unroll
        for (int k0 = 0; k0 < 8; k0++) {
          acc0a = __builtin_amdgcn_mfma_f32_16x16x32_bf16(a[k0], Bw[k0], acc0a, 0, 0, 0);
          acc1a = __builtin_amdgcn_mfma_f32_16x16x32_bf16(a[k0], Bw[16 + k0], acc1a, 0, 0, 0);
        }
        wait_vm0(); __builtin_amdgcn_sched_barrier(0);
#pragma unroll
        for (int k0 = 8; k0 < 16; k0++) {
          acc0b = __builtin_amdgcn_mfma_f32_16x16x32_bf16(a[k0], Bw[k0], acc0b, 0, 0, 0);
          acc1b = __builtin_amdgcn_mfma_f32_16x16x32_bf16(a[k0], Bw[16 + k0], acc1b, 0, 0, 0);
        }
      }

      // epilogue: acc0 = r|z, acc1 = in|hn; pair via shfl_xor(8); m<8 stores
      float v0[4], v1[4], o0[4], o1[4];
#pragma unroll
      for (int q = 0; q < 4; q++) {
        v0[q] = acc0a[q] + acc0b[q];
        v1[q] = acc1a[q] + acc1b[q];
        o0[q] = __shfl_xor(v0[q], 8);
        o1[q] = __shfl_xor(v1[q], 8);
      }
      if (m < 8) {
        char* pc = (char*)&g_hstage[(t + 1) & 7][srow][hc];
        unsigned short us[4];
#pragma unroll
        for (int q = 0; q < 4; q++) {
          float r = sigmoidf_(v0[q]);
          float z = sigmoidf_(o0[q]);
          float n = tanhf_(v1[q] + r * o1[q]);
          float hn = (1.f - z) * n + z * hcar[q];
          bf16 hv = (bf16)hn;
          hcar[q] = (float)hv;
          us[q] = __builtin_bit_cast(unsigned short, hv);
        }
        if (fast) {
          bf16* pp = (bf16*)pc;
#pragma unroll
          for (int q = 0; q < 4; q++) pp[q * Hd] = __builtin_bit_cast(bf16, us[q]);
        } else {
          st_u16_cohere<0>(pc, us[0]);    st_u16_cohere<1024>(pc, us[1]);
          st_u16_cohere<2048>(pc, us[2]); st_u16_cohere<3072>(pc, us[3]);
        }
      }
      wait_vm0();                 // this chain's stage stores at coherence point
      if (l == 0) atomic_inc(cnt);
    }

    // ---- history flush every 8 steps: both chains' own slices, 16B rows ----
    if ((t & 7) == 7) {
      const int s = l >> 3;                                // slot 0..7
      const int v = (t + 1) - (((t + 1) - s) & 7);
      const int r0A = rgA * 16 + (l & 7) * 2;
      const int r0B = rgB * 16 + (l & 7) * 2;
      const char* spA = (const char*)&g_hstage[s][r0A][hbase];
      const char* spB = (const char*)&g_hstage[s][r0B][hbase];
      bf16x8 xa0, xa1, xb0, xb1;
      if (fast) {
        xa0 = ld_b16x8_l2<0>(spA); xa1 = ld_b16x8_l2<1024>(spA);
        xb0 = ld_b16x8_l2<0>(spB); xb1 = ld_b16x8_l2<1024>(spB);
      } else {
        xa0 = ld_b16x8_cohere<0>(spA); xa1 = ld_b16x8_cohere<1024>(spA);
        xb0 = ld_b16x8_cohere<0>(spB); xb1 = ld_b16x8_cohere<1024>(spB);
      }
      wait_vm0(); __builtin_amdgcn_sched_barrier(0);
      char* dpA = (char*)&g_hbuf[v][r0A][hbase];
      char* dpB = (char*)&g_hbuf[v][r0B][hbase];
      *(bf16x8*)(dpA)        = xa0;
      *(bf16x8*)(dpA + 1024) = xa1;
      *(bf16x8*)(dpB)        = xb0;
      *(bf16x8*)(dpB + 1024) = xb1;
    }
  }
  wait_vm0();  // all stores (incl. final flush) complete before kernel end
}

// ---------- projection: out[b][v][t] = sum_k h[t+1][b][k] * w_proj[k][v] + b_proj[v] ----------
__global__ __launch_bounds__(256) void k_proj(const float* b_proj, float* out) {
  int b = blockIdx.x;
  int w = threadIdx.x >> 6, l = threadIdx.x & 63;
  int tt = blockIdx.y * 4 + w;
  if (tt > 12) return;
  int m = l & 15, ksub = (l >> 4) * 8;
  int tcol = tt * 16 + m;
  int trow = (tcol < Td ? tcol : Td - 1) + 1;  // clamp pad cols (masked on store)

  f32x4 acc[7];
#pragma unroll
  for (int f = 0; f < 7; f++)
#pragma unroll
    for (int i = 0; i < 4; i++) {
      int v = f * 16 + (l >> 4) * 4 + i;
      acc[f][i] = (v < Vd) ? b_proj[v] : 0.f;
    }

  bf16x8 bb[16];
  const bf16* Bp = &g_hbuf[trow][b][ksub];
#pragma unroll
  for (int k0 = 0; k0 < 16; k0++) bb[k0] = *(const bf16x8*)(Bp + k0 * 32);

#pragma unroll
  for (int k0 = 0; k0 < 16; k0++)
#pragma unroll
    for (int f = 0; f < 7; f++) {
      bf16x8 afrag = *(const bf16x8*)&g_wprojt[f * 16 + m][k0 * 32 + ksub];
      acc[f] = __builtin_amdgcn_mfma_f32_16x16x32_bf16(afrag, bb[k0], acc[f], 0, 0, 0);
    }

  if (tcol < Td) {
#pragma unroll
    for (int f = 0; f < 7; f++)
#pragma unroll
      for (int i = 0; i < 4; i++) {
        int v = f * 16 + (l >> 4) * 4 + i;
        if (v < Vd) out[((size_t)b * Vd + v) * Td + tcol] = acc[f][i];
      }
  }
}

// ---------- launch ----------
extern "C" void kernel_launch(void* const* d_in, const int* in_sizes, int n_in,
                              void* d_out, int out_size, void* d_ws, size_t ws_size,
                              hipStream_t stream) {
  const float* feat   = (const float*)d_in[0];
  const float* w_hp   = (const float*)d_in[1];
  const float* b_hp   = (const float*)d_in[2];
  const float* embed  = (const float*)d_in[3];
  const float* w_ih   = (const float*)d_in[4];
  const float* w_hh   = (const float*)d_in[5];
  const float* b_ih   = (const float*)d_in[6];
  const float* b_hh   = (const float*)d_in[7];
  const float* w_proj = (const float*)d_in[8];
  const float* b_proj = (const float*)d_in[9];
  float* out = (float*)d_out;

  hipLaunchKernelGGL(k_conv_feat, dim3((Bsz * FEAT) / 256), dim3(256), 0, stream, feat);
  hipLaunchKernelGGL(k_gi0, dim3(3 * Hd), dim3(64), 0, stream, embed, w_ih, b_ih);
  hipLaunchKernelGGL(k_build_wt1, dim3(Gd), dim3(256), 0, stream, w_ih, w_hh, b_ih, b_hh);
  hipLaunchKernelGGL(k_build_wt0, dim3(Gd), dim3(256), 0, stream, w_hh, b_hh);
  hipLaunchKernelGGL(k_build_whpt, dim3(Hd), dim3(256), 0, stream, w_hp);
  hipLaunchKernelGGL(k_build_wprojt, dim3(112), dim3(256), 0, stream, w_proj);
  hipLaunchKernelGGL(k_gru_seq, dim3(256), dim3(256), 0, stream, b_hp);
  hipLaunchKernelGGL(k_proj, dim3(Bsz, 4), dim3(256), 0, stream, b_proj, out);
}

// Round 12
// 950.061 us; speedup vs baseline: 1.6835x; 1.6835x over previous
//
#include <hip/hip_runtime.h>

#define Bsz  512
#define FEAT 2048
#define Hd   512
#define Vd   100
#define Td   200
#define Gd   2048   // 4*H interleaved gate columns: per 16-col group [r|z|i_n|h_n]

typedef __bf16 bf16;
typedef __bf16 bf16x8 __attribute__((ext_vector_type(8)));
typedef float  f32x4  __attribute__((ext_vector_type(4)));

// Static device storage. Rewritten every launch -> deterministic across replays.
__device__ bf16  g_hbuf[Td + 1][Bsz][Hd];   // h history (k_proj input); background stores
__device__ bf16  g_hping[2][Bsz][Hd];       // L2-hot ping-pong h for the recurrence
__device__ bf16  g_wt0[Gd][Hd];             // step-0 weights   [gatecol][k]
__device__ bf16  g_wt1[Gd][Hd];             // steps>=1 weights [gatecol][k]
__device__ float g_bias0[Gd];
__device__ float g_bias1[Gd];
__device__ bf16  g_featbf[Bsz][FEAT];
__device__ bf16  g_whpt[Hd][FEAT];          // w_hp transposed: [n][k]
__device__ bf16  g_wprojt[112][Hd];         // w_proj transposed+padded: [v][k]
__device__ float g_gi0[3 * Hd];             // embed[SOS] @ w_ih.T + b_ih
__device__ unsigned g_flags[32][8];         // [rowgroup][colblock] L3 publish/fallback flags
__device__ unsigned g_dbar[32][16];         // [rowgroup][0]: fast arrival counter (64B apart)
__device__ unsigned g_xcd[256];             // published XCC_ID per block

// ---------- device-coherent (L3, sc0 sc1) helpers — slow path ----------
template <int OFF>
__device__ __forceinline__ bf16x8 ld_b16x8_cohere(const void* p) {
  bf16x8 r;
  asm volatile("global_load_dwordx4 %0, %1, off offset:%2 sc0 sc1"
               : "=&v"(r) : "v"(p), "i"(OFF) : "memory");
  return r;
}
// ---------- agent-scope (L1-bypass, L2-hit, sc1) loads — fast-path A ----------
// sc0 = workgroup scope (L1-cached; round-4 measured stale), sc1 = agent scope
// (bypasses L1, reads the XCD-shared L2 = the fast path's coherence point).
template <int OFF>
__device__ __forceinline__ bf16x8 ld_b16x8_l2(const void* p) {
  bf16x8 r;
  asm volatile("global_load_dwordx4 %0, %1, off offset:%2 sc1"
               : "=&v"(r) : "v"(p), "i"(OFF) : "memory");
  return r;
}
template <int OFF>
__device__ __forceinline__ void st_u16_cohere(void* p, unsigned short v) {
  asm volatile("global_store_short %0, %1, off offset:%2 sc0 sc1"
               :: "v"(p), "v"(v), "i"(OFF) : "memory");
}
__device__ __forceinline__ void st_u32_cohere(void* p, unsigned v) {
  asm volatile("global_store_dword %0, %1, off sc0 sc1" :: "v"(p), "v"(v) : "memory");
}
__device__ __forceinline__ unsigned ld_u32_cohere(const void* p) {
  unsigned r;
  asm volatile("global_load_dword %0, %1, off sc0 sc1\n\ts_waitcnt vmcnt(0)"
               : "=&v"(r) : "v"(p) : "memory");
  return r;
}
// ---------- atomic helpers ----------
// LESSON (round 4): plain/sc0 loads can spin forever on L1-stale flag lines;
// only an atomic RMW is architecturally guaranteed to observe peer updates.
__device__ __forceinline__ unsigned atomic_rd(unsigned* p) {   // RMW read at L2
  unsigned r;
  asm volatile("global_atomic_add %0, %1, %2, off sc0\n\ts_waitcnt vmcnt(0)"
               : "=&v"(r) : "v"(p), "v"(0u) : "memory");
  return r;
}
__device__ __forceinline__ void atomic_inc(unsigned* p) {      // no-return add
  asm volatile("global_atomic_add %0, %1, off" :: "v"(p), "v"(1u) : "memory");
}
__device__ __forceinline__ void wait_vm0() { asm volatile("s_waitcnt vmcnt(0)" ::: "memory"); }
__device__ __forceinline__ void wait_vm8() { asm volatile("s_waitcnt vmcnt(8)" ::: "memory"); }

#define LDA16(arr, base) do {                                                   \
  arr[0]  = ld_b16x8_cohere<0>(base);   arr[1]  = ld_b16x8_cohere<64>(base);    \
  arr[2]  = ld_b16x8_cohere<128>(base); arr[3]  = ld_b16x8_cohere<192>(base);   \
  arr[4]  = ld_b16x8_cohere<256>(base); arr[5]  = ld_b16x8_cohere<320>(base);   \
  arr[6]  = ld_b16x8_cohere<384>(base); arr[7]  = ld_b16x8_cohere<448>(base);   \
  arr[8]  = ld_b16x8_cohere<512>(base); arr[9]  = ld_b16x8_cohere<576>(base);   \
  arr[10] = ld_b16x8_cohere<640>(base); arr[11] = ld_b16x8_cohere<704>(base);   \
  arr[12] = ld_b16x8_cohere<768>(base); arr[13] = ld_b16x8_cohere<832>(base);   \
  arr[14] = ld_b16x8_cohere<896>(base); arr[15] = ld_b16x8_cohere<960>(base);   \
} while (0)

#define LDA16_L2(arr, base) do {                                                \
  arr[0]  = ld_b16x8_l2<0>(base);   arr[1]  = ld_b16x8_l2<64>(base);            \
  arr[2]  = ld_b16x8_l2<128>(base); arr[3]  = ld_b16x8_l2<192>(base);           \
  arr[4]  = ld_b16x8_l2<256>(base); arr[5]  = ld_b16x8_l2<320>(base);           \
  arr[6]  = ld_b16x8_l2<384>(base); arr[7]  = ld_b16x8_l2<448>(base);           \
  arr[8]  = ld_b16x8_l2<512>(base); arr[9]  = ld_b16x8_l2<576>(base);           \
  arr[10] = ld_b16x8_l2<640>(base); arr[11] = ld_b16x8_l2<704>(base);           \
  arr[12] = ld_b16x8_l2<768>(base); arr[13] = ld_b16x8_l2<832>(base);           \
  arr[14] = ld_b16x8_l2<896>(base); arr[15] = ld_b16x8_l2<960>(base);           \
} while (0)

__device__ __forceinline__ float sigmoidf_(float x) {
  x = fminf(fmaxf(x, -30.f), 30.f);
  return 1.f / (1.f + __expf(-x));
}
__device__ __forceinline__ float tanhf_(float x) {
  x = fminf(fmaxf(x, -15.f), 15.f);
  float e = __expf(2.f * x);
  return (e - 1.f) / (e + 1.f);
}

// Slow-path / publish barrier: device scope through L3 (placement-independent).
// 8 col-blocks per 16-row group.
__device__ __forceinline__ void group_barrier(int rg, int cg, unsigned phase) {
  wait_vm0();
  __syncthreads();
  if (threadIdx.x == 0) st_u32_cohere(&g_flags[rg][cg], phase);
  if (threadIdx.x < 64) {
    const unsigned* fp = &g_flags[rg][threadIdx.x & 7];
    while (ld_u32_cohere(fp) < phase) __builtin_amdgcn_s_sleep(1);
  }
  __syncthreads();
}

// ---------- prep kernels ----------

__global__ void k_conv_feat(const float* feat) {
  int i = blockIdx.x * 256 + threadIdx.x;
  if (i < Bsz * FEAT) ((bf16*)g_featbf)[i] = (bf16)feat[i];
  if (blockIdx.x == 0) {  // reset sync state each replay
    ((unsigned*)g_flags)[threadIdx.x] = 0u;
    ((unsigned*)g_dbar)[threadIdx.x] = 0u;
    ((unsigned*)g_dbar)[256 + threadIdx.x] = 0u;
    g_xcd[threadIdx.x] = 0xffffffffu;
  }
}

__global__ void k_gi0(const float* embed, const float* w_ih, const float* b_ih) {
  int j = blockIdx.x;
  const float* wr = w_ih + (size_t)j * Hd;
  float s = 0.f;
  for (int k = threadIdx.x; k < Hd; k += 64) s += embed[k] * wr[k];
#pragma unroll
  for (int off = 32; off > 0; off >>= 1) s += __shfl_down(s, off);
  if (threadIdx.x == 0) g_gi0[j] = s + b_ih[j];
}

// FUSED wt0+wt1 build. gate col c: group g=c/64 (16 h-cols), f=(c>>4)&3 in
// {r,z,i_n,h_n}, j = g*16 + (c&15). wt1 = pre-summed (w_ih+w_hh) for r,z;
// wt0 = w_hh-only with i_n zeroed (step-0 gi is constant, folded into bias0).
__global__ void k_build_w(const float* w_ih, const float* w_hh,
                          const float* b_ih, const float* b_hh) {
  int c = blockIdx.x;
  int j = (c >> 6) * 16 + (c & 15);
  int f = (c >> 4) & 3;
  const float* s1 = nullptr; const float* s2 = nullptr;  // wt1 sources
  const float* s0 = nullptr;                             // wt0 source
  float bias1, bias0;
  if (f == 0) {
    s1 = w_ih + (size_t)j * Hd; s2 = w_hh + (size_t)j * Hd; s0 = s2;
    bias1 = b_ih[j] + b_hh[j];                 bias0 = g_gi0[j] + b_hh[j];
  } else if (f == 1) {
    s1 = w_ih + (size_t)(Hd + j) * Hd; s2 = w_hh + (size_t)(Hd + j) * Hd; s0 = s2;
    bias1 = b_ih[Hd + j] + b_hh[Hd + j];       bias0 = g_gi0[Hd + j] + b_hh[Hd + j];
  } else if (f == 2) {
    s1 = w_ih + (size_t)(2 * Hd + j) * Hd;     s0 = nullptr;
    bias1 = b_ih[2 * Hd + j];                  bias0 = g_gi0[2 * Hd + j];
  } else {
    s1 = w_hh + (size_t)(2 * Hd + j) * Hd;     s0 = s1;
    bias1 = b_hh[2 * Hd + j];                  bias0 = b_hh[2 * Hd + j];
  }
  for (int k = threadIdx.x; k < Hd; k += 256) {
    g_wt1[c][k] = (bf16)(s1[k] + (s2 ? s2[k] : 0.f));
    g_wt0[c][k] = (bf16)(s0 ? s0[k] : 0.f);
  }
  if (threadIdx.x == 0) { g_bias1[c] = bias1; g_bias0[c] = bias0; }
}

// FUSED transpose build: blocks 0..511 -> whpt row, 512..623 -> wprojt row.
__global__ void k_build_t(const float* w_hp, const float* w_proj) {
  int n = blockIdx.x;
  if (n < Hd) {
    for (int k = threadIdx.x; k < FEAT; k += 256)
      g_whpt[n][k] = (bf16)w_hp[(size_t)k * Hd + n];
  } else {
    int v = n - Hd;  // 0..111
    for (int k = threadIdx.x; k < Hd; k += 256)
      g_wprojt[v][k] = (bf16)(v < Vd ? w_proj[(size_t)k * Vd + v] : 0.f);
  }
}

// ---------- persistent kernel: h0 + all 200 GRU steps (round-9 structure) ----------
// TRANSPOSED decomposition: block = 16 rows x 64 hcols (4 waves x different
// 64-gatecol groups, SAME 16 rows). A 16-row group is covered by only 8
// col-blocks -> sync domain 8: 8 incs + 8 pollers per counter, skew over 8
// blocks. rg=(bid&7)*4+((bid>>3)&3) keeps all 8 blocks of a rowgroup on one
// XCD under round-robin (bid%8 fixed); runtime-verified, L3 fallback.
__global__ __launch_bounds__(256, 1) void k_gru_seq(const float* b_hp) {
  const int bid = blockIdx.x;
  const int rg = (bid & 7) * 4 + ((bid >> 3) & 3);  // 0..31: rows rg*16..+16
  const int cg = bid >> 5;                          // 0..7 : hcols cg*64..+64
  const int w = threadIdx.x >> 6, l = threadIdx.x & 63;
  const int m = l & 15;
  const int ksub = (l >> 4) * 8;
  const int colb = (cg * 4 + w) * 64;               // this wave's 64 gatecols
  const int arow = rg * 16 + m;
  const int srow = rg * 16 + (l >> 4) * 4;
  const int hcol = (cg * 4 + w) * 16 + m;
  __shared__ int s_fast;

  // persistent B-fragments for steps >= 1 (4 gates x 16 k-chunks)
  bf16x8 Bw[64];
#pragma unroll
  for (int f = 0; f < 4; f++)
#pragma unroll
    for (int k0 = 0; k0 < 16; k0++)
      Bw[f * 16 + k0] = *(const bf16x8*)&g_wt1[colb + f * 16 + m][k0 * 32 + ksub];

  float b0v[4], b1v[4];
#pragma unroll
  for (int f = 0; f < 4; f++) {
    b0v[f] = g_bias0[colb + f * 16 + m];
    b1v[f] = g_bias1[colb + f * 16 + m];
  }

  // ---- publish XCC_ID, decide fast/slow per row group ----
  unsigned xcc;
  asm volatile("s_getreg_b32 %0, hwreg(HW_REG_XCC_ID)" : "=s"(xcc));
  if (threadIdx.x == 0) st_u32_cohere(&g_xcd[bid], xcc);
  group_barrier(rg, cg, 1u);  // publish complete (L3 scope)
  if (threadIdx.x < 64) {
    int c = threadIdx.x & 7;
    unsigned peer = ld_u32_cohere(&g_xcd[(rg >> 2) + ((rg & 3) << 3) + (c << 5)]);
    unsigned long long bal = __ballot(peer == xcc);
    if (threadIdx.x == 0) s_fast = ((bal & 0xffull) == 0xffull) ? 1 : 0;
  }
  __syncthreads();
  const bool fast = (s_fast != 0);

  // ---- h0 = feat @ w_hp + b_hp (this wave: 16 rows x its 16 hcols, K=2048) ----
  float hcarry[4];
  {
    f32x4 acc = {0.f, 0.f, 0.f, 0.f};
#pragma unroll 4
    for (int k0 = 0; k0 < FEAT; k0 += 32) {
      bf16x8 a = *(const bf16x8*)&g_featbf[arow][k0 + ksub];
      bf16x8 b = *(const bf16x8*)&g_whpt[hcol][k0 + ksub];
      acc = __builtin_amdgcn_mfma_f32_16x16x32_bf16(a, b, acc, 0, 0, 0);
    }
    float bhp = b_hp[hcol];
    unsigned short us[4];
#pragma unroll
    for (int i = 0; i < 4; i++) {
      bf16 hv = (bf16)(acc[i] + bhp);
      hcarry[i] = (float)hv;
      us[i] = __builtin_bit_cast(unsigned short, hv);
    }
    if (fast) {
      bf16* pp = &g_hping[0][srow][hcol];
#pragma unroll
      for (int i = 0; i < 4; i++) pp[i * Hd] = __builtin_bit_cast(bf16, us[i]);
    } else {
      char* pc = (char*)&g_hbuf[0][srow][hcol];
      st_u16_cohere<0>(pc, us[0]);    st_u16_cohere<1024>(pc, us[1]);
      st_u16_cohere<2048>(pc, us[2]); st_u16_cohere<3072>(pc, us[3]);
    }
  }

  if (fast) {
    unsigned* cnt = &g_dbar[rg][0];
    // h0 barrier (target 8)
    wait_vm0();
    __syncthreads();
    if (threadIdx.x == 0) {
      atomic_inc(cnt);
      while (atomic_rd(cnt) < 8u) { }
    }
    __syncthreads();

    for (int t = 0; t < Td; t++) {
      // A-slice of h[t] from the L2-hot ping slot, agent-scope loads
      bf16x8 a[16];
      const char* Ap = (const char*)&g_hping[t & 1][arow][ksub];
      LDA16_L2(a, Ap);

      f32x4 acc[4], acc2[4];
#pragma unroll
      for (int f = 0; f < 4; f++) {
        float bv = (t == 0) ? b0v[f] : b1v[f];
        acc[f]  = (f32x4){bv, bv, bv, bv};
        acc2[f] = (f32x4){0.f, 0.f, 0.f, 0.f};
      }
      wait_vm8(); __builtin_amdgcn_sched_barrier(0);   // a[0..7] landed
      if (t == 0) {  // step-0 weight set streamed from cache once
#pragma unroll
        for (int k0 = 0; k0 < 8; k0++)
#pragma unroll
          for (int f = 0; f < 4; f++) {
            bf16x8 b = *(const bf16x8*)&g_wt0[colb + f * 16 + m][k0 * 32 + ksub];
            acc[f] = __builtin_amdgcn_mfma_f32_16x16x32_bf16(a[k0], b, acc[f], 0, 0, 0);
          }
        wait_vm0(); __builtin_amdgcn_sched_barrier(0);
#pragma unroll
        for (int k0 = 8; k0 < 16; k0++)
#pragma unroll
          for (int f = 0; f < 4; f++) {
            bf16x8 b = *(const bf16x8*)&g_wt0[colb + f * 16 + m][k0 * 32 + ksub];
            acc2[f] = __builtin_amdgcn_mfma_f32_16x16x32_bf16(a[k0], b, acc2[f], 0, 0, 0);
          }
      } else {
#pragma unroll
        for (int k0 = 0; k0 < 8; k0++)
#pragma unroll
          for (int f = 0; f < 4; f++)
            acc[f] = __builtin_amdgcn_mfma_f32_16x16x32_bf16(a[k0], Bw[f * 16 + k0], acc[f], 0, 0, 0);
        wait_vm0(); __builtin_amdgcn_sched_barrier(0);
#pragma unroll
        for (int k0 = 8; k0 < 16; k0++)
#pragma unroll
          for (int f = 0; f < 4; f++)
            acc2[f] = __builtin_amdgcn_mfma_f32_16x16x32_bf16(a[k0], Bw[f * 16 + k0], acc2[f], 0, 0, 0);
      }

      // fused GRU epilogue
      bf16 hv4[4];
      bf16* pp = &g_hping[(t + 1) & 1][srow][hcol];
#pragma unroll
      for (int i = 0; i < 4; i++) {
        float r = sigmoidf_(acc[0][i] + acc2[0][i]);
        float z = sigmoidf_(acc[1][i] + acc2[1][i]);
        float n = tanhf_((acc[2][i] + acc2[2][i]) + r * (acc[3][i] + acc2[3][i]));
        float hn = (1.f - z) * n + z * hcarry[i];
        bf16 hv = (bf16)hn;
        hcarry[i] = (float)hv;
        hv4[i] = hv;
        pp[i * Hd] = hv;          // L2-hot ping store (the one the drain waits on)
      }
      wait_vm0();                 // ping stores at the XCD coherence point

      // background history store: issued after drain, RFO overlaps barrier/next step
      bf16* ph = &g_hbuf[t + 1][srow][hcol];
#pragma unroll
      for (int i = 0; i < 4; i++) ph[i * Hd] = hv4[i];

      if (t < Td - 1) {
        __syncthreads();
        if (threadIdx.x == 0) {
          atomic_inc(cnt);
          unsigned tgt = 8u * (unsigned)(t + 2);
          while (atomic_rd(cnt) < tgt) { }
        }
        __syncthreads();
      }
    }
  } else {
    group_barrier(rg, cg, 2u);  // h0 complete (L3 scope)
    for (int t = 0; t < Td; t++) {
      bf16x8 a[16];
      const char* Ap = (const char*)&g_hbuf[t][arow][ksub];
      LDA16(a, Ap);

      f32x4 acc[4];
#pragma unroll
      for (int f = 0; f < 4; f++) {
        float bv = (t == 0) ? b0v[f] : b1v[f];
        acc[f] = (f32x4){bv, bv, bv, bv};
      }
      if (t == 0) {
        wait_vm0(); __builtin_amdgcn_sched_barrier(0);
#pragma unroll
        for (int k0 = 0; k0 < 16; k0++)
#pragma unroll
          for (int f = 0; f < 4; f++) {
            bf16x8 b = *(const bf16x8*)&g_wt0[colb + f * 16 + m][k0 * 32 + ksub];
            acc[f] = __builtin_amdgcn_mfma_f32_16x16x32_bf16(a[k0], b, acc[f], 0, 0, 0);
          }
      } else {
        wait_vm8(); __builtin_amdgcn_sched_barrier(0);
#pragma unroll
        for (int k0 = 0; k0 < 8; k0++)
#pragma unroll
          for (int f = 0; f < 4; f++)
            acc[f] = __builtin_amdgcn_mfma_f32_16x16x32_bf16(a[k0], Bw[f * 16 + k0], acc[f], 0, 0, 0);
        wait_vm0(); __builtin_amdgcn_sched_barrier(0);
#pragma unroll
        for (int k0 = 8; k0 < 16; k0++)
#pragma unroll
          for (int f = 0; f < 4; f++)
            acc[f] = __builtin_amdgcn_mfma_f32_16x16x32_bf16(a[k0], Bw[f * 16 + k0], acc[f], 0, 0, 0);
      }

      char* pb = (char*)&g_hbuf[t + 1][srow][hcol];
      unsigned short us[4];
#pragma unroll
      for (int i = 0; i < 4; i++) {
        float r = sigmoidf_(acc[0][i]);
        float z = sigmoidf_(acc[1][i]);
        float n = tanhf_(acc[2][i] + r * acc[3][i]);
        float hn = (1.f - z) * n + z * hcarry[i];
        bf16 hv = (bf16)hn;
        hcarry[i] = (float)hv;
        us[i] = __builtin_bit_cast(unsigned short, hv);
      }
      st_u16_cohere<0>(pb, us[0]);    st_u16_cohere<1024>(pb, us[1]);
      st_u16_cohere<2048>(pb, us[2]); st_u16_cohere<3072>(pb, us[3]);

      if (t < Td - 1) group_barrier(rg, cg, (unsigned)(t + 3));
    }
  }
  wait_vm0();  // all h stores (incl. final history) complete before kernel end
}

// ---------- projection: out[b][v][t] = sum_k h[t+1][b][k] * w_proj[k][v] + b_proj[v] ----------
__global__ __launch_bounds__(256) void k_proj(const float* b_proj, float* out) {
  int b = blockIdx.x;
  int w = threadIdx.x >> 6, l = threadIdx.x & 63;
  int tt = blockIdx.y * 4 + w;
  if (tt > 12) return;
  int m = l & 15, ksub = (l >> 4) * 8;
  int tcol = tt * 16 + m;
  int trow = (tcol < Td ? tcol : Td - 1) + 1;  // clamp pad cols (masked on store)

  f32x4 acc[7];
#pragma unroll
  for (int f = 0; f < 7; f++)
#pragma unroll
    for (int i = 0; i < 4; i++) {
      int v = f * 16 + (l >> 4) * 4 + i;
      acc[f][i] = (v < Vd) ? b_proj[v] : 0.f;
    }

  bf16x8 bb[16];
  const bf16* Bp = &g_hbuf[trow][b][ksub];
#pragma unroll
  for (int k0 = 0; k0 < 16; k0++) bb[k0] = *(const bf16x8*)(Bp + k0 * 32);

#pragma unroll
  for (int k0 = 0; k0 < 16; k0++)
#pragma unroll
    for (int f = 0; f < 7; f++) {
      bf16x8 afrag = *(const bf16x8*)&g_wprojt[f * 16 + m][k0 * 32 + ksub];
      acc[f] = __builtin_amdgcn_mfma_f32_16x16x32_bf16(afrag, bb[k0], acc[f], 0, 0, 0);
    }

  if (tcol < Td) {
#pragma unroll
    for (int f = 0; f < 7; f++)
#pragma unroll
      for (int i = 0; i < 4; i++) {
        int v = f * 16 + (l >> 4) * 4 + i;
        if (v < Vd) out[((size_t)b * Vd + v) * Td + tcol] = acc[f][i];
      }
  }
}

// ---------- launch ----------
extern "C" void kernel_launch(void* const* d_in, const int* in_sizes, int n_in,
                              void* d_out, int out_size, void* d_ws, size_t ws_size,
                              hipStream_t stream) {
  const float* feat   = (const float*)d_in[0];
  const float* w_hp   = (const float*)d_in[1];
  const float* b_hp   = (const float*)d_in[2];
  const float* embed  = (const float*)d_in[3];
  const float* w_ih   = (const float*)d_in[4];
  const float* w_hh   = (const float*)d_in[5];
  const float* b_ih   = (const float*)d_in[6];
  const float* b_hh   = (const float*)d_in[7];
  const float* w_proj = (const float*)d_in[8];
  const float* b_proj = (const float*)d_in[9];
  float* out = (float*)d_out;

  hipLaunchKernelGGL(k_conv_feat, dim3((Bsz * FEAT) / 256), dim3(256), 0, stream, feat);
  hipLaunchKernelGGL(k_gi0, dim3(3 * Hd), dim3(64), 0, stream, embed, w_ih, b_ih);
  hipLaunchKernelGGL(k_build_w, dim3(Gd), dim3(256), 0, stream, w_ih, w_hh, b_ih, b_hh);
  hipLaunchKernelGGL(k_build_t, dim3(Hd + 112), dim3(256), 0, stream, w_hp, w_proj);
  hipLaunchKernelGGL(k_gru_seq, dim3(256), dim3(256), 0, stream, b_hp);
  hipLaunchKernelGGL(k_proj, dim3(Bsz, 4), dim3(256), 0, stream, b_proj, out);
}